// Round 1
// baseline (5214.841 us; speedup 1.0000x reference)
//
#include <hip/hip_runtime.h>
#include <math.h>

#define B_    512
#define T_    75
#define IN_   768
#define H_    256
#define NSPAN 8
#define OUTD  2
#define NDAYS 10
#define EPS_  1e-5f
#define MAXN_ 0.999f
#define CLIP_ (1.0f - 1e-7f)

// ---------------- wave helpers (wave = 64 lanes) ----------------
__device__ __forceinline__ float wred(float v) {
#pragma unroll
    for (int o = 32; o > 0; o >>= 1) v += __shfl_xor(v, o, 64);
    return v;
}
__device__ __forceinline__ float artanh_(float x) {
    x = fminf(x, CLIP_);
    return 0.5f * logf((1.f + x) / (1.f - x));
}
__device__ __forceinline__ float sigm_(float x) { return 1.f / (1.f + expf(-x)); }

// ---------------- prep kernels ----------------
// expmap0 of enc_bias rows (3,H) -> bv
__global__ __launch_bounds__(256) void k_bias(const float* __restrict__ eb, float* __restrict__ bv) {
    int wid = threadIdx.x >> 6, lane = threadIdx.x & 63;
    if (wid >= 3) return;
    const float* p = eb + wid * H_;
    float v0 = p[lane], v1 = p[lane + 64], v2 = p[lane + 128], v3 = p[lane + 192];
    float ss = wred(v0 * v0 + v1 * v1 + v2 * v2 + v3 * v3);
    float n = sqrtf(fmaxf(ss, 1e-15f));
    float nc = fmaxf(n, EPS_);
    float s = tanhf(nc) / nc;
    float nv = n * s;
    if (nv > MAXN_) s *= MAXN_ / nv;
    bv[wid * H_ + lane] = v0 * s;
    bv[wid * H_ + lane + 64] = v1 * s;
    bv[wid * H_ + lane + 128] = v2 * s;
    bv[wid * H_ + lane + 192] = v3 * s;
}

// WT[k][j] = enc_w_hh[j][k]  (256 x 768)
__global__ __launch_bounds__(256) void k_transpose(const float* __restrict__ W, float* __restrict__ WT) {
    int k = blockIdx.x; // 0..255
    for (int j = threadIdx.x; j < 768; j += 256)
        WT[(size_t)k * 768 + j] = W[(size_t)j * 256 + k];
}

// per-row expmap0 scale of x: xs = total scale, xn = ||expmap0(x)|| maxed with EPS
__global__ __launch_bounds__(256) void k_row_scale(const float* __restrict__ x, float* __restrict__ xs, float* __restrict__ xn) {
    int wid = threadIdx.x >> 6, lane = threadIdx.x & 63;
    int row = blockIdx.x * 4 + wid;
    const float* p = x + (size_t)row * IN_;
    float ss = 0.f;
#pragma unroll
    for (int q = 0; q < 12; ++q) { float v = p[lane + 64 * q]; ss = fmaf(v, v, ss); }
    ss = wred(ss);
    float n = sqrtf(fmaxf(ss, 1e-15f));
    float nc = fmaxf(n, EPS_);
    float s = tanhf(nc) / nc;
    float nv = n * s;
    if (nv > MAXN_) s *= MAXN_ / nv;
    if (lane == 0) { xs[row] = s; xn[row] = fmaxf(n * s, EPS_); }
}

// finish mobius_matvec on precomputed raw MX (per row, per gate block of 256)
__global__ __launch_bounds__(256) void k_ux_scale(float* __restrict__ MX, const float* __restrict__ xs, const float* __restrict__ xnb) {
    int wid = threadIdx.x >> 6, lane = threadIdx.x & 63;
    int rg = blockIdx.x * 4 + wid;
    int row = rg / 3, g = rg - row * 3;
    float s = xs[row], xv = xnb[row];
    float* p = MX + (size_t)row * IN_ + g * H_;
    float v0 = p[lane] * s, v1 = p[lane + 64] * s, v2 = p[lane + 128] * s, v3 = p[lane + 192] * s;
    float ss = wred(v0 * v0 + v1 * v1 + v2 * v2 + v3 * v3);
    float mxn = fmaxf(sqrtf(fmaxf(ss, 1e-15f)), EPS_);
    float tt = tanhf(mxn / xv * artanh_(xv));
    float sc = tt / mxn;
    if (tt > MAXN_) sc = MAXN_ / mxn;
    p[lane] = v0 * sc; p[lane + 64] = v1 * sc; p[lane + 128] = v2 * sc; p[lane + 192] = v3 * sc;
}

// ---------------- generic f32 GEMM: C = A @ B^T (+bias)(+relu) ----------------
// A:(M,K) lda; B:(N,K) row-major; C:(M,N). M%128==0, N%128==0, K%16==0.
#define BM 128
#define BN 128
#define BKK 16
__global__ __launch_bounds__(256) void k_gemm_bt(
    const float* __restrict__ A, int lda,
    const float* __restrict__ Bm,
    const float* __restrict__ bias,
    float* __restrict__ C,
    int N, int K, int act)
{
    __shared__ float As[BKK][BM + 4];
    __shared__ float Bs[BKK][BN + 4];
    int tid = threadIdx.x;
    int m0 = blockIdx.y * BM, n0 = blockIdx.x * BN;
    int lr = tid >> 2;
    int lc = (tid & 3) << 2;
    int row0 = (tid >> 4) << 3;
    int col0 = (tid & 15) << 3;
    float acc[8][8];
#pragma unroll
    for (int i = 0; i < 8; ++i)
#pragma unroll
        for (int j = 0; j < 8; ++j) acc[i][j] = 0.f;

    for (int k0 = 0; k0 < K; k0 += BKK) {
        float4 a0 = *(const float4*)&A[(size_t)(m0 + lr) * lda + k0 + lc];
        float4 a1 = *(const float4*)&A[(size_t)(m0 + lr + 64) * lda + k0 + lc];
        float4 b0 = *(const float4*)&Bm[(size_t)(n0 + lr) * K + k0 + lc];
        float4 b1 = *(const float4*)&Bm[(size_t)(n0 + lr + 64) * K + k0 + lc];
        __syncthreads();
        As[lc + 0][lr] = a0.x; As[lc + 1][lr] = a0.y; As[lc + 2][lr] = a0.z; As[lc + 3][lr] = a0.w;
        As[lc + 0][lr + 64] = a1.x; As[lc + 1][lr + 64] = a1.y; As[lc + 2][lr + 64] = a1.z; As[lc + 3][lr + 64] = a1.w;
        Bs[lc + 0][lr] = b0.x; Bs[lc + 1][lr] = b0.y; Bs[lc + 2][lr] = b0.z; Bs[lc + 3][lr] = b0.w;
        Bs[lc + 0][lr + 64] = b1.x; Bs[lc + 1][lr + 64] = b1.y; Bs[lc + 2][lr + 64] = b1.z; Bs[lc + 3][lr + 64] = b1.w;
        __syncthreads();
#pragma unroll
        for (int k = 0; k < BKK; ++k) {
            float4 x0 = *(const float4*)&As[k][row0];
            float4 x1 = *(const float4*)&As[k][row0 + 4];
            float4 y0 = *(const float4*)&Bs[k][col0];
            float4 y1 = *(const float4*)&Bs[k][col0 + 4];
            float xa[8] = {x0.x, x0.y, x0.z, x0.w, x1.x, x1.y, x1.z, x1.w};
            float yb[8] = {y0.x, y0.y, y0.z, y0.w, y1.x, y1.y, y1.z, y1.w};
#pragma unroll
            for (int i = 0; i < 8; ++i)
#pragma unroll
                for (int j = 0; j < 8; ++j) acc[i][j] = fmaf(xa[i], yb[j], acc[i][j]);
        }
    }
    float bvv[8];
#pragma unroll
    for (int j = 0; j < 8; ++j) bvv[j] = bias ? bias[n0 + col0 + j] : 0.f;
#pragma unroll
    for (int i = 0; i < 8; ++i) {
        float vv[8];
#pragma unroll
        for (int j = 0; j < 8; ++j) {
            float v = acc[i][j] + bvv[j];
            vv[j] = act ? fmaxf(v, 0.f) : v;
        }
        size_t base = (size_t)(m0 + row0 + i) * N + n0 + col0;
        *(float4*)&C[base] = make_float4(vv[0], vv[1], vv[2], vv[3]);
        *(float4*)&C[base + 4] = make_float4(vv[4], vv[5], vv[6], vv[7]);
    }
}

// ---------------- mobius wave-level primitives (row = one wave, 256 elems) ----------------
__device__ __forceinline__ void mv_finish(float* X, float xn, int lane) {
    float ss = 0.f;
#pragma unroll
    for (int q = 0; q < 4; ++q) { float v = X[lane + 64 * q]; ss = fmaf(v, v, ss); }
    float mxn = fmaxf(sqrtf(fmaxf(wred(ss), 1e-15f)), EPS_);
    float tt = tanhf(mxn / xn * artanh_(xn));
    float sc = tt / mxn;
    if (tt > MAXN_) sc = MAXN_ / mxn;
#pragma unroll
    for (int q = 0; q < 4; ++q) X[lane + 64 * q] *= sc;
}

// X <- project(mobius_add(X, Y))   (in place)
__device__ __forceinline__ void madd(float* X, const float* Y, int lane) {
    float x2 = 0.f, y2 = 0.f, xy = 0.f;
#pragma unroll
    for (int q = 0; q < 4; ++q) {
        float xv = X[lane + 64 * q], yv = Y[lane + 64 * q];
        x2 = fmaf(xv, xv, x2); y2 = fmaf(yv, yv, y2); xy = fmaf(xv, yv, xy);
    }
    x2 = wred(x2); y2 = wred(y2); xy = wred(xy);
    float den = fmaxf(1.f + 2.f * xy + x2 * y2, EPS_);
    float cx = 1.f + 2.f * xy + y2, cy = 1.f - x2;
    float nn = 0.f;
#pragma unroll
    for (int q = 0; q < 4; ++q) {
        int j = lane + 64 * q;
        float nv = cx * X[j] + cy * Y[j];
        X[j] = nv;
        nn = fmaf(nv, nv, nn);
    }
    nn = wred(nn);
    float pn = sqrtf(fmaxf(nn / (den * den), 1e-15f));
    float s = 1.f / den;
    if (pn > MAXN_) s *= MAXN_ / pn;
#pragma unroll
    for (int q = 0; q < 4; ++q) X[lane + 64 * q] *= s;
}

__device__ __forceinline__ void lsig(float* X, int lane) {
    float ss = 0.f;
#pragma unroll
    for (int q = 0; q < 4; ++q) { float v = X[lane + 64 * q]; ss = fmaf(v, v, ss); }
    float n = fmaxf(sqrtf(fmaxf(wred(ss), 1e-15f)), EPS_);
    float s = artanh_(n) / n;
#pragma unroll
    for (int q = 0; q < 4; ++q) { int j = lane + 64 * q; X[j] = 1.f / (1.f + expf(-X[j] * s)); }
}

// O <- project(mobius_pointwise_mul(W, Xv))
__device__ __forceinline__ void pmul(const float* W, const float* Xv, float* O, int lane) {
    float xs2 = 0.f;
#pragma unroll
    for (int q = 0; q < 4; ++q) { float v = Xv[lane + 64 * q]; xs2 = fmaf(v, v, xs2); }
    float xn = fmaxf(sqrtf(fmaxf(wred(xs2), 1e-15f)), EPS_);
    float ws2 = 0.f;
#pragma unroll
    for (int q = 0; q < 4; ++q) {
        int j = lane + 64 * q;
        float v = W[j] * Xv[j];
        O[j] = v;
        ws2 = fmaf(v, v, ws2);
    }
    float wxn = fmaxf(sqrtf(fmaxf(wred(ws2), 1e-15f)), EPS_);
    float tt = tanhf(wxn / xn * artanh_(xn));
    float sc = tt / wxn;
    if (tt > MAXN_) sc = MAXN_ / wxn;
#pragma unroll
    for (int q = 0; q < 4; ++q) O[lane + 64 * q] *= sc;
}

// ---------------- mobius GRU encoder: 8 batch rows / block, all 75 steps in-kernel ----------------
__global__ __launch_bounds__(512) void k_encoder(
    const float* __restrict__ UX, const float* __restrict__ WT,
    const float* __restrict__ bv, float* __restrict__ Hfull)
{
    __shared__ float h_s[8][256], A_s[8][256], B_s[8][256], C_s[8][256], D_s[8][256], P_s[8][256];
    __shared__ float br_s[256], bh_s[256], bz_s[256];
    int tid = threadIdx.x;
    int wid = tid >> 6, lane = tid & 63;
    int b0 = blockIdx.x * 8;
    for (int i = tid; i < 256; i += 512) { br_s[i] = bv[i]; bh_s[i] = bv[256 + i]; bz_s[i] = bv[512 + i]; }
    for (int i = tid; i < 2048; i += 512) ((float*)h_s)[i] = 0.f;
    __syncthreads();
    int col = tid & 255, hi = tid >> 8;
    float* hp = h_s[wid]; float* Ap = A_s[wid]; float* Bp = B_s[wid];
    float* Cp = C_s[wid]; float* Dp = D_s[wid];

    for (int t = 0; t < T_; ++t) {
        // phase1: raw matvec h@W^T for r (hi=0, cols 0:256) and z (hi=1, cols 512:768)
        {
            const float* wp = WT + (hi ? 512 + col : col);
            float a[8] = {0, 0, 0, 0, 0, 0, 0, 0};
#pragma unroll 4
            for (int k = 0; k < 256; k += 4) {
                float w0 = wp[(size_t)(k + 0) * 768];
                float w1 = wp[(size_t)(k + 1) * 768];
                float w2 = wp[(size_t)(k + 2) * 768];
                float w3 = wp[(size_t)(k + 3) * 768];
#pragma unroll
                for (int r = 0; r < 8; ++r) {
                    const float4 hv = *(const float4*)&h_s[r][k];
                    a[r] = fmaf(hv.x, w0, fmaf(hv.y, w1, fmaf(hv.z, w2, fmaf(hv.w, w3, a[r]))));
                }
            }
            if (hi) {
#pragma unroll
                for (int r = 0; r < 8; ++r) A_s[r][col] = a[r];
            } else {
#pragma unroll
                for (int r = 0; r < 8; ++r) B_s[r][col] = a[r];
            }
        }
        __syncthreads();
        // elementwise 1: wave = row
        const float* uxrow = UX + ((size_t)(b0 + wid) * T_ + t) * IN_;
        float ss = 0.f;
#pragma unroll
        for (int q = 0; q < 4; ++q) { float v = hp[lane + 64 * q]; ss = fmaf(v, v, ss); }
        float hn = fmaxf(sqrtf(fmaxf(wred(ss), 1e-15f)), EPS_);
        // z gate (A)
        mv_finish(Ap, hn, lane);
#pragma unroll
        for (int q = 0; q < 4; ++q) Dp[lane + 64 * q] = uxrow[512 + lane + 64 * q];
        madd(Ap, Dp, lane);
        madd(Ap, bz_s, lane);
        lsig(Ap, lane);
        // r gate (B)
        mv_finish(Bp, hn, lane);
#pragma unroll
        for (int q = 0; q < 4; ++q) Dp[lane + 64 * q] = uxrow[lane + 64 * q];
        madd(Bp, Dp, lane);
        madd(Bp, br_s, lane);
        lsig(Bp, lane);
        // rh -> C
        pmul(Bp, hp, Cp, lane);
        __syncthreads();
        // phase2: raw matvec rh@W_hhh^T (cols 256:512), k split across the two thread-halves
        float p[8] = {0, 0, 0, 0, 0, 0, 0, 0};
        {
            const float* wp = WT + 256 + col;
            int kb = hi * 128;
#pragma unroll 4
            for (int k = kb; k < kb + 128; k += 4) {
                float w0 = wp[(size_t)(k + 0) * 768];
                float w1 = wp[(size_t)(k + 1) * 768];
                float w2 = wp[(size_t)(k + 2) * 768];
                float w3 = wp[(size_t)(k + 3) * 768];
#pragma unroll
                for (int r = 0; r < 8; ++r) {
                    const float4 cv = *(const float4*)&C_s[r][k];
                    p[r] = fmaf(cv.x, w0, fmaf(cv.y, w1, fmaf(cv.z, w2, fmaf(cv.w, w3, p[r]))));
                }
            }
        }
        if (hi) {
#pragma unroll
            for (int r = 0; r < 8; ++r) P_s[r][col] = p[r];
        }
        __syncthreads();
        if (!hi) {
#pragma unroll
            for (int r = 0; r < 8; ++r) B_s[r][col] = p[r] + P_s[r][col];
        }
        __syncthreads();
        // elementwise 2
        ss = 0.f;
#pragma unroll
        for (int q = 0; q < 4; ++q) { float v = Cp[lane + 64 * q]; ss = fmaf(v, v, ss); }
        float rhn = fmaxf(sqrtf(fmaxf(wred(ss), 1e-15f)), EPS_);
        mv_finish(Bp, rhn, lane);
#pragma unroll
        for (int q = 0; q < 4; ++q) Dp[lane + 64 * q] = uxrow[256 + lane + 64 * q];
        madd(Bp, Dp, lane);
        madd(Bp, bh_s, lane);          // B = h_tilde
#pragma unroll
        for (int q = 0; q < 4; ++q) Dp[lane + 64 * q] = -hp[lane + 64 * q];
        madd(Dp, Bp, lane);            // D = delta = mobius_add(-h, h_tilde)
        pmul(Ap, Dp, Cp, lane);        // C = mobius z*delta
        madd(hp, Cp, lane);            // h = mobius_add(h, C)
        float* orow = Hfull + ((size_t)(b0 + wid) * T_ + t) * H_;
#pragma unroll
        for (int q = 0; q < 4; ++q) orow[lane + 64 * q] = hp[lane + 64 * q];
        __syncthreads();
    }
}

// logmap0 in place over (rows, 256)
__global__ __launch_bounds__(256) void k_logmap(float* __restrict__ Y) {
    int wid = threadIdx.x >> 6, lane = threadIdx.x & 63;
    int row = blockIdx.x * 4 + wid;
    float* p = Y + (size_t)row * H_;
    float v0 = p[lane], v1 = p[lane + 64], v2 = p[lane + 128], v3 = p[lane + 192];
    float ss = wred(v0 * v0 + v1 * v1 + v2 * v2 + v3 * v3);
    float n = fmaxf(sqrtf(fmaxf(ss, 1e-15f)), EPS_);
    float s = artanh_(n) / n;
    p[lane] = v0 * s; p[lane + 64] = v1 * s; p[lane + 128] = v2 * s; p[lane + 192] = v3 * s;
}

// score[b,t] = v . tanh(S1 + b1 + q[b]) + bv, masked
__global__ __launch_bounds__(256) void k_score(
    const float* __restrict__ S1, const float* __restrict__ q,
    const float* __restrict__ b1, const float* __restrict__ av,
    const float* __restrict__ abv, const int* __restrict__ len,
    float* __restrict__ sc)
{
    int wid = threadIdx.x >> 6, lane = threadIdx.x & 63;
    int row = blockIdx.x * 4 + wid;
    int b = row / T_, t = row - b * T_;
    const float* s1 = S1 + (size_t)row * H_;
    const float* qp = q + (size_t)b * H_;
    float part = 0.f;
#pragma unroll
    for (int qq = 0; qq < 4; ++qq) {
        int j = lane + 64 * qq;
        float u = tanhf(s1[j] + b1[j] + qp[j]);
        part = fmaf(u, av[j], part);
    }
    part = wred(part) + abv[0];
    if (t >= len[b]) part = -1e9f;
    if (lane == 0) sc[row] = part;
}

// per-b: softmax over T, ctx = sum w*full, span logits + softmax -> d_out
__global__ __launch_bounds__(256) void k_ctx(
    const float* __restrict__ sc, const float* __restrict__ full,
    const float* __restrict__ spw, const float* __restrict__ spb,
    float* __restrict__ ctx, float* __restrict__ outsp)
{
    int b = blockIdx.x, tid = threadIdx.x;
    __shared__ float w_s[T_];
    __shared__ float cs[H_];
    __shared__ float red[NSPAN];
    if (tid < T_) w_s[tid] = sc[b * T_ + tid];
    __syncthreads();
    if (tid == 0) {
        float mx = -1e30f;
        for (int t = 0; t < T_; ++t) mx = fmaxf(mx, w_s[t]);
        float sum = 0.f;
        for (int t = 0; t < T_; ++t) { float e = expf(w_s[t] - mx); w_s[t] = e; sum += e; }
        float inv = 1.f / sum;
        for (int t = 0; t < T_; ++t) w_s[t] *= inv;
    }
    __syncthreads();
    float c = 0.f;
    for (int t = 0; t < T_; ++t) c = fmaf(w_s[t], full[((size_t)b * T_ + t) * H_ + tid], c);
    ctx[(size_t)b * H_ + tid] = c;
    cs[tid] = c;
    __syncthreads();
    if (tid < NSPAN) {
        float lg = spb[tid];
        for (int j = 0; j < H_; ++j) lg = fmaf(spw[tid * H_ + j], cs[j], lg);
        red[tid] = lg;
    }
    __syncthreads();
    if (tid == 0) {
        float mx = red[0];
        for (int k2 = 1; k2 < NSPAN; ++k2) mx = fmaxf(mx, red[k2]);
        float sum = 0.f;
        for (int k2 = 0; k2 < NSPAN; ++k2) sum += expf(red[k2] - mx);
        float inv = 1.f / sum;
        for (int k2 = 0; k2 < NSPAN; ++k2) outsp[(size_t)b * NSPAN + k2] = expf(red[k2] - mx) * inv;
    }
}

// Euclidean GRU cell + fc_out softmax
__global__ __launch_bounds__(256) void k_dec_cell(
    const float* __restrict__ gi, const float* __restrict__ gh,
    float* __restrict__ h, const float* __restrict__ fow,
    const float* __restrict__ fob, float* __restrict__ outp, int t)
{
    int b = blockIdx.x, j = threadIdx.x;
    __shared__ float hs[H_];
    __shared__ float red[2];
    size_t gb = (size_t)b * 768;
    float r = sigm_(gi[gb + j] + gh[gb + j]);
    float z = sigm_(gi[gb + 256 + j] + gh[gb + 256 + j]);
    float n = tanhf(fmaf(r, gh[gb + 512 + j], gi[gb + 512 + j]));
    float hv = h[(size_t)b * H_ + j];
    float hnew = (1.f - z) * n + z * hv;
    h[(size_t)b * H_ + j] = hnew;
    hs[j] = hnew;
    __syncthreads();
    int wid = j >> 6, lane = j & 63;
    if (wid < 2) {
        float p = 0.f;
#pragma unroll
        for (int q = 0; q < 4; ++q) { int c = lane + 64 * q; p = fmaf(fow[wid * H_ + c], hs[c], p); }
        p = wred(p);
        if (lane == 0) red[wid] = p + fob[wid];
    }
    __syncthreads();
    if (j == 0) {
        float l0 = red[0], l1 = red[1];
        float mx = fmaxf(l0, l1);
        float e0 = expf(l0 - mx), e1 = expf(l1 - mx);
        float inv = 1.f / (e0 + e1);
        outp[(size_t)b * (NDAYS * OUTD) + t * OUTD + 0] = e0 * inv;
        outp[(size_t)b * (NDAYS * OUTD) + t * OUTD + 1] = e1 * inv;
    }
}

extern "C" void kernel_launch(void* const* d_in, const int* in_sizes, int n_in,
                              void* d_out, int out_size, void* d_ws, size_t ws_size,
                              hipStream_t stream)
{
    (void)in_sizes; (void)n_in; (void)out_size; (void)ws_size;
    const float* x        = (const float*)d_in[0];
    const int*   len      = (const int*)  d_in[1];
    const float* enc_w_ih = (const float*)d_in[2];
    const float* enc_w_hh = (const float*)d_in[3];
    const float* enc_bias = (const float*)d_in[4];
    const float* dec_w_ih = (const float*)d_in[5];
    const float* dec_w_hh = (const float*)d_in[6];
    const float* dec_b_ih = (const float*)d_in[7];
    const float* dec_b_hh = (const float*)d_in[8];
    const float* attn_w1  = (const float*)d_in[9];
    const float* attn_b1  = (const float*)d_in[10];
    const float* attn_w2  = (const float*)d_in[11];
    const float* attn_b2  = (const float*)d_in[12];
    const float* attn_v   = (const float*)d_in[13];
    const float* attn_bv  = (const float*)d_in[14];
    const float* fc_in_w  = (const float*)d_in[15];
    const float* fc_in_b  = (const float*)d_in[16];
    const float* fc_out_w = (const float*)d_in[17];
    const float* fc_out_b = (const float*)d_in[18];
    const float* span_w   = (const float*)d_in[19];
    const float* span_b   = (const float*)d_in[20];
    float* out = (float*)d_out;
    float* wsf = (float*)d_ws;

    const size_t ROWS = (size_t)B_ * T_;            // 38400
    float* UX    = wsf;                             // 38400*768
    float* Hfull = UX + ROWS * IN_;                 // 38400*256
    float* xs    = Hfull + ROWS * H_;               // 38400
    float* xnb   = xs + ROWS;                       // 38400
    float* WT    = xnb + ROWS;                      // 256*768
    float* bvv   = WT + 256 * 768;                  // 768
    float* qbuf  = bvv + 768;                       // 512*256
    float* scb   = qbuf + (size_t)B_ * H_;          // 38400
    float* ctx   = scb + ROWS;                      // 512*256 (doubles as decoder h)
    // UX region reused after encoder/attention consume it:
    float* S1  = UX;
    float* gi  = UX;
    float* gh  = UX + (size_t)B_ * 768;
    float* inp = UX + 2 * (size_t)B_ * 768;

    k_bias<<<1, 256, 0, stream>>>(enc_bias, bvv);
    k_transpose<<<256, 256, 0, stream>>>(enc_w_hh, WT);
    k_row_scale<<<(unsigned)(ROWS / 4), 256, 0, stream>>>(x, xs, xnb);
    k_gemm_bt<<<dim3(IN_ / BN, (unsigned)(ROWS / BM)), 256, 0, stream>>>(x, IN_, enc_w_ih, nullptr, UX, IN_, IN_, 0);
    k_ux_scale<<<(unsigned)(ROWS * 3 / 4), 256, 0, stream>>>(UX, xs, xnb);
    k_encoder<<<B_ / 8, 512, 0, stream>>>(UX, WT, bvv, Hfull);
    k_logmap<<<(unsigned)(ROWS / 4), 256, 0, stream>>>(Hfull);
    // q = hx @ w2^T + b2   (hx rows are the t=T-1 rows of logmapped Hfull, stride T*H)
    k_gemm_bt<<<dim3(H_ / BN, B_ / BM), 256, 0, stream>>>(Hfull + (T_ - 1) * H_, T_ * H_, attn_w2, attn_b2, qbuf, H_, H_, 0);
    k_gemm_bt<<<dim3(H_ / BN, (unsigned)(ROWS / BM)), 256, 0, stream>>>(Hfull, H_, attn_w1, nullptr, S1, H_, H_, 0);
    k_score<<<(unsigned)(ROWS / 4), 256, 0, stream>>>(S1, qbuf, attn_b1, attn_v, attn_bv, len, scb);
    k_ctx<<<B_, 256, 0, stream>>>(scb, Hfull, span_w, span_b, ctx, out);
    hipMemsetAsync(inp, 0, (size_t)B_ * 768 * sizeof(float), stream);
    for (int t = 0; t < NDAYS; ++t) {
        k_gemm_bt<<<dim3(768 / BN, B_ / BM), 256, 0, stream>>>(inp, 768, dec_w_ih, dec_b_ih, gi, 768, 768, 0);
        k_gemm_bt<<<dim3(768 / BN, B_ / BM), 256, 0, stream>>>(ctx, H_, dec_w_hh, dec_b_hh, gh, 768, H_, 0);
        k_dec_cell<<<B_, 256, 0, stream>>>(gi, gh, ctx, fc_out_w, fc_out_b, out + B_ * NSPAN, t);
        if (t + 1 < NDAYS)
            k_gemm_bt<<<dim3(768 / BN, B_ / BM), 256, 0, stream>>>(ctx, H_, fc_in_w, fc_in_b, inp, 768, H_, 1);
    }
}

// Round 2
// 5103.045 us; speedup vs baseline: 1.0219x; 1.0219x over previous
//
#include <hip/hip_runtime.h>
#include <math.h>

#define B_    512
#define T_    75
#define IN_   768
#define H_    256
#define NSPAN 8
#define OUTD  2
#define NDAYS 10
#define EPS_  1e-5f
#define MAXN_ 0.999f
#define CLIP_ (1.0f - 1e-7f)

// ---------------- wave helpers (wave = 64 lanes) ----------------
__device__ __forceinline__ float wred(float v) {
#pragma unroll
    for (int o = 32; o > 0; o >>= 1) v += __shfl_xor(v, o, 64);
    return v;
}
__device__ __forceinline__ float artanh_(float x) {
    x = fminf(x, CLIP_);
    return 0.5f * logf((1.f + x) / (1.f - x));
}
__device__ __forceinline__ float sigm_(float x) { return 1.f / (1.f + expf(-x)); }

// -------- register-array mobius primitives (one wave owns a 256-vector, 4/lane) --------
__device__ __forceinline__ float rnorm4(const float* v) {
    float ss = 0.f;
#pragma unroll
    for (int q = 0; q < 4; ++q) ss = fmaf(v[q], v[q], ss);
    ss = wred(ss);
    return sqrtf(fmaxf(ss, 1e-15f));
}
// v <- project(tanh(|v|/xn * artanh(xn)) * v/|v|)   (finish of mobius_matvec)
__device__ __forceinline__ void mv_finish_reg(float* v, float xn) {
    float n = fmaxf(rnorm4(v), EPS_);
    float tt = tanhf(n / xn * artanh_(xn));
    float sc = tt / n;
    if (tt > MAXN_) sc = MAXN_ / n;
#pragma unroll
    for (int q = 0; q < 4; ++q) v[q] *= sc;
}
// x <- project(mobius_add(x, y))
__device__ __forceinline__ void madd_reg(float* x, const float* y) {
    float x2 = 0.f, y2 = 0.f, xy = 0.f;
#pragma unroll
    for (int q = 0; q < 4; ++q) {
        x2 = fmaf(x[q], x[q], x2);
        y2 = fmaf(y[q], y[q], y2);
        xy = fmaf(x[q], y[q], xy);
    }
    x2 = wred(x2); y2 = wred(y2); xy = wred(xy);
    float den = fmaxf(1.f + 2.f * xy + x2 * y2, EPS_);
    float cx = 1.f + 2.f * xy + y2, cy = 1.f - x2;
    float nn = 0.f;
#pragma unroll
    for (int q = 0; q < 4; ++q) {
        float nv = cx * x[q] + cy * y[q];
        x[q] = nv;
        nn = fmaf(nv, nv, nn);
    }
    nn = wred(nn);
    float pn = sqrtf(fmaxf(nn, 1e-15f)) / den;
    float s = 1.f / den;
    if (pn > MAXN_) s *= MAXN_ / pn;
#pragma unroll
    for (int q = 0; q < 4; ++q) x[q] *= s;
}
// v <- sigmoid(logmap0(v))
__device__ __forceinline__ void lsig_reg(float* v) {
    float n = fmaxf(rnorm4(v), EPS_);
    float s = artanh_(n) / n;
#pragma unroll
    for (int q = 0; q < 4; ++q) v[q] = 1.f / (1.f + expf(-v[q] * s));
}
// o <- project(mobius_pointwise_mul(w, x)); optional out norm (clamped to >=EPS)
__device__ __forceinline__ void pmul_reg(const float* w, const float* x, float* o, float* onorm) {
    float xn = fmaxf(rnorm4(x), EPS_);
#pragma unroll
    for (int q = 0; q < 4; ++q) o[q] = w[q] * x[q];
    float wxn = fmaxf(rnorm4(o), EPS_);
    float tt = tanhf(wxn / xn * artanh_(xn));
    float sc = tt / wxn;
    float nrm = tt;
    if (tt > MAXN_) { sc = MAXN_ / wxn; nrm = MAXN_; }
#pragma unroll
    for (int q = 0; q < 4; ++q) o[q] *= sc;
    if (onorm) *onorm = fmaxf(nrm, EPS_);
}

// ---------------- prep kernels ----------------
__global__ __launch_bounds__(256) void k_bias(const float* __restrict__ eb, float* __restrict__ bv) {
    int wid = threadIdx.x >> 6, lane = threadIdx.x & 63;
    if (wid >= 3) return;
    const float* p = eb + wid * H_;
    float v0 = p[lane], v1 = p[lane + 64], v2 = p[lane + 128], v3 = p[lane + 192];
    float ss = wred(v0 * v0 + v1 * v1 + v2 * v2 + v3 * v3);
    float n = sqrtf(fmaxf(ss, 1e-15f));
    float nc = fmaxf(n, EPS_);
    float s = tanhf(nc) / nc;
    float nv = n * s;
    if (nv > MAXN_) s *= MAXN_ / nv;
    bv[wid * H_ + lane] = v0 * s;
    bv[wid * H_ + lane + 64] = v1 * s;
    bv[wid * H_ + lane + 128] = v2 * s;
    bv[wid * H_ + lane + 192] = v3 * s;
}

__global__ __launch_bounds__(256) void k_transpose(const float* __restrict__ W, float* __restrict__ WT) {
    int k = blockIdx.x; // 0..255
    for (int j = threadIdx.x; j < 768; j += 256)
        WT[(size_t)k * 768 + j] = W[(size_t)j * 256 + k];
}

__global__ __launch_bounds__(256) void k_row_scale(const float* __restrict__ x, float* __restrict__ xs, float* __restrict__ xn) {
    int wid = threadIdx.x >> 6, lane = threadIdx.x & 63;
    int row = blockIdx.x * 4 + wid;
    const float* p = x + (size_t)row * IN_;
    float ss = 0.f;
#pragma unroll
    for (int q = 0; q < 12; ++q) { float v = p[lane + 64 * q]; ss = fmaf(v, v, ss); }
    ss = wred(ss);
    float n = sqrtf(fmaxf(ss, 1e-15f));
    float nc = fmaxf(n, EPS_);
    float s = tanhf(nc) / nc;
    float nv = n * s;
    if (nv > MAXN_) s *= MAXN_ / nv;
    if (lane == 0) { xs[row] = s; xn[row] = fmaxf(n * s, EPS_); }
}

__global__ __launch_bounds__(256) void k_ux_scale(float* __restrict__ MX, const float* __restrict__ xs, const float* __restrict__ xnb) {
    int wid = threadIdx.x >> 6, lane = threadIdx.x & 63;
    int rg = blockIdx.x * 4 + wid;
    int row = rg / 3, g = rg - row * 3;
    float s = xs[row], xv = xnb[row];
    float* p = MX + (size_t)row * IN_ + g * H_;
    float v0 = p[lane] * s, v1 = p[lane + 64] * s, v2 = p[lane + 128] * s, v3 = p[lane + 192] * s;
    float ss = wred(v0 * v0 + v1 * v1 + v2 * v2 + v3 * v3);
    float mxn = fmaxf(sqrtf(fmaxf(ss, 1e-15f)), EPS_);
    float tt = tanhf(mxn / xv * artanh_(xv));
    float sc = tt / mxn;
    if (tt > MAXN_) sc = MAXN_ / mxn;
    p[lane] = v0 * sc; p[lane + 64] = v1 * sc; p[lane + 128] = v2 * sc; p[lane + 192] = v3 * sc;
}

// ---------------- generic f32 GEMM (128x128 tile): C = A @ B^T (+bias)(+relu) ----------------
#define BM 128
#define BN 128
#define BKK 16
__global__ __launch_bounds__(256) void k_gemm_bt(
    const float* __restrict__ A, int lda,
    const float* __restrict__ Bm,
    const float* __restrict__ bias,
    float* __restrict__ C,
    int N, int K, int act)
{
    __shared__ float As[BKK][BM + 4];
    __shared__ float Bs[BKK][BN + 4];
    int tid = threadIdx.x;
    int m0 = blockIdx.y * BM, n0 = blockIdx.x * BN;
    int lr = tid >> 2;
    int lc = (tid & 3) << 2;
    int row0 = (tid >> 4) << 3;
    int col0 = (tid & 15) << 3;
    float acc[8][8];
#pragma unroll
    for (int i = 0; i < 8; ++i)
#pragma unroll
        for (int j = 0; j < 8; ++j) acc[i][j] = 0.f;

    for (int k0 = 0; k0 < K; k0 += BKK) {
        float4 a0 = *(const float4*)&A[(size_t)(m0 + lr) * lda + k0 + lc];
        float4 a1 = *(const float4*)&A[(size_t)(m0 + lr + 64) * lda + k0 + lc];
        float4 b0 = *(const float4*)&Bm[(size_t)(n0 + lr) * K + k0 + lc];
        float4 b1 = *(const float4*)&Bm[(size_t)(n0 + lr + 64) * K + k0 + lc];
        __syncthreads();
        As[lc + 0][lr] = a0.x; As[lc + 1][lr] = a0.y; As[lc + 2][lr] = a0.z; As[lc + 3][lr] = a0.w;
        As[lc + 0][lr + 64] = a1.x; As[lc + 1][lr + 64] = a1.y; As[lc + 2][lr + 64] = a1.z; As[lc + 3][lr + 64] = a1.w;
        Bs[lc + 0][lr] = b0.x; Bs[lc + 1][lr] = b0.y; Bs[lc + 2][lr] = b0.z; Bs[lc + 3][lr] = b0.w;
        Bs[lc + 0][lr + 64] = b1.x; Bs[lc + 1][lr + 64] = b1.y; Bs[lc + 2][lr + 64] = b1.z; Bs[lc + 3][lr + 64] = b1.w;
        __syncthreads();
#pragma unroll
        for (int k = 0; k < BKK; ++k) {
            float4 x0 = *(const float4*)&As[k][row0];
            float4 x1 = *(const float4*)&As[k][row0 + 4];
            float4 y0 = *(const float4*)&Bs[k][col0];
            float4 y1 = *(const float4*)&Bs[k][col0 + 4];
            float xa[8] = {x0.x, x0.y, x0.z, x0.w, x1.x, x1.y, x1.z, x1.w};
            float yb[8] = {y0.x, y0.y, y0.z, y0.w, y1.x, y1.y, y1.z, y1.w};
#pragma unroll
            for (int i = 0; i < 8; ++i)
#pragma unroll
                for (int j = 0; j < 8; ++j) acc[i][j] = fmaf(xa[i], yb[j], acc[i][j]);
        }
    }
    float bvv[8];
#pragma unroll
    for (int j = 0; j < 8; ++j) bvv[j] = bias ? bias[n0 + col0 + j] : 0.f;
#pragma unroll
    for (int i = 0; i < 8; ++i) {
        float vv[8];
#pragma unroll
        for (int j = 0; j < 8; ++j) {
            float v = acc[i][j] + bvv[j];
            vv[j] = act ? fmaxf(v, 0.f) : v;
        }
        size_t base = (size_t)(m0 + row0 + i) * N + n0 + col0;
        *(float4*)&C[base] = make_float4(vv[0], vv[1], vv[2], vv[3]);
        *(float4*)&C[base + 4] = make_float4(vv[4], vv[5], vv[6], vv[7]);
    }
}

// ---------------- small-tile f32 GEMM (64x64, BK=32, 256 thr) for M=512 layers ----------------
__global__ __launch_bounds__(256) void k_gemm_bt64(
    const float* __restrict__ A, int lda,
    const float* __restrict__ Bm,
    const float* __restrict__ bias,
    float* __restrict__ C,
    int N, int K, int act)
{
    __shared__ float As[32][64 + 4];
    __shared__ float Bs[32][64 + 4];
    int tid = threadIdx.x;
    int m0 = blockIdx.y * 64, n0 = blockIdx.x * 64;
    int lr = tid >> 2;            // 0..63
    int lc = (tid & 3) << 3;      // 0,8,16,24
    int row0 = (tid >> 4) << 2;   // 0..60
    int col0 = (tid & 15) << 2;   // 0..60
    float acc[4][4];
#pragma unroll
    for (int i = 0; i < 4; ++i)
#pragma unroll
        for (int j = 0; j < 4; ++j) acc[i][j] = 0.f;

    for (int k0 = 0; k0 < K; k0 += 32) {
        float4 a0 = *(const float4*)&A[(size_t)(m0 + lr) * lda + k0 + lc];
        float4 a1 = *(const float4*)&A[(size_t)(m0 + lr) * lda + k0 + lc + 4];
        float4 b0 = *(const float4*)&Bm[(size_t)(n0 + lr) * K + k0 + lc];
        float4 b1 = *(const float4*)&Bm[(size_t)(n0 + lr) * K + k0 + lc + 4];
        __syncthreads();
        As[lc + 0][lr] = a0.x; As[lc + 1][lr] = a0.y; As[lc + 2][lr] = a0.z; As[lc + 3][lr] = a0.w;
        As[lc + 4][lr] = a1.x; As[lc + 5][lr] = a1.y; As[lc + 6][lr] = a1.z; As[lc + 7][lr] = a1.w;
        Bs[lc + 0][lr] = b0.x; Bs[lc + 1][lr] = b0.y; Bs[lc + 2][lr] = b0.z; Bs[lc + 3][lr] = b0.w;
        Bs[lc + 4][lr] = b1.x; Bs[lc + 5][lr] = b1.y; Bs[lc + 6][lr] = b1.z; Bs[lc + 7][lr] = b1.w;
        __syncthreads();
#pragma unroll
        for (int k = 0; k < 32; ++k) {
            float4 xa = *(const float4*)&As[k][row0];
            float4 yb = *(const float4*)&Bs[k][col0];
            float xv[4] = {xa.x, xa.y, xa.z, xa.w};
            float yv[4] = {yb.x, yb.y, yb.z, yb.w};
#pragma unroll
            for (int i = 0; i < 4; ++i)
#pragma unroll
                for (int j = 0; j < 4; ++j) acc[i][j] = fmaf(xv[i], yv[j], acc[i][j]);
        }
    }
    float bvv[4];
#pragma unroll
    for (int j = 0; j < 4; ++j) bvv[j] = bias ? bias[n0 + col0 + j] : 0.f;
#pragma unroll
    for (int i = 0; i < 4; ++i) {
        float vv[4];
#pragma unroll
        for (int j = 0; j < 4; ++j) {
            float v = acc[i][j] + bvv[j];
            vv[j] = act ? fmaxf(v, 0.f) : v;
        }
        *(float4*)&C[(size_t)(m0 + row0 + i) * N + n0 + col0] = make_float4(vv[0], vv[1], vv[2], vv[3]);
    }
}

// ---------------- mobius GRU encoder v2: 4 rows/block, 128 blocks, register-tiled matvec ----------------
// Phase1 (r,z): each thread owns 8 cols x 32 k, acc[4 rows][8 cols]; partials -> P[r][ks][c0..511].
// Phase2 (h):   each thread owns 4 cols x 32 k; partials -> P[r][ks][c0..255].
// Elementwise: wave w (w<4) owns row w; h lives in wave registers; mobius ops via shfl reductions.
__global__ __launch_bounds__(512) void k_encoder(
    const float* __restrict__ UX, const float* __restrict__ WT,
    const float* __restrict__ bv, float* __restrict__ Hfull)
{
    __shared__ float h32[4][256];
    __shared__ float C32[4][256];
    __shared__ float P_s[4][8][512];    // 64KB partial buffer (phase1 uses c<512, phase2 c<256)
    __shared__ float bias_s[3][256];    // [0]=b_r, [1]=b_h, [2]=b_z

    int tid = threadIdx.x;
    int wid = tid >> 6, lane = tid & 63;
    int b0 = blockIdx.x * 4;

    for (int i = tid; i < 768; i += 512) bias_s[i >> 8][i & 255] = bv[i];
    for (int i = tid; i < 1024; i += 512) ((float*)h32)[i] = 0.f;
    __syncthreads();

    // phase1 mapping: cg in 0..63 (8 cols), ks in 0..7 (32 k)
    int cg = tid & 63, ks = tid >> 6;
    int p1c0 = cg * 8;                             // 0..504 in P-col space
    int wcol1 = (p1c0 < 256) ? p1c0 : p1c0 + 256;  // r gate cols 0..255 / z gate cols 512..767
    const float* w1 = WT + wcol1;
    int k10 = ks * 32;
    // phase2 mapping: 4 cols
    int p2c0 = (tid & 63) * 4;                     // 0..252
    const float* w2 = WT + 256 + p2c0;             // h gate cols 256..511
    int k20 = ks * 32;

    int row = wid;  // elementwise row (valid when wid<4)
    float hreg[4] = {0.f, 0.f, 0.f, 0.f};
    float zv[4];
    float rhn = EPS_;

    for (int t = 0; t < T_; ++t) {
        // ---- phase1: raw h @ {W_hr, W_hz}^T ----
        {
            float acc[4][8];
#pragma unroll
            for (int r = 0; r < 4; ++r)
#pragma unroll
                for (int c = 0; c < 8; ++c) acc[r][c] = 0.f;
            for (int kk = 0; kk < 32; kk += 4) {
                int k = k10 + kk;
                float4 hv[4];
#pragma unroll
                for (int r = 0; r < 4; ++r) hv[r] = *(const float4*)&h32[r][k];
#pragma unroll
                for (int i = 0; i < 4; ++i) {
                    const float4 wa = *(const float4*)&w1[(size_t)(k + i) * 768];
                    const float4 wb = *(const float4*)&w1[(size_t)(k + i) * 768 + 4];
#pragma unroll
                    for (int r = 0; r < 4; ++r) {
                        const float h = ((const float*)&hv[r])[i];
                        acc[r][0] = fmaf(h, wa.x, acc[r][0]);
                        acc[r][1] = fmaf(h, wa.y, acc[r][1]);
                        acc[r][2] = fmaf(h, wa.z, acc[r][2]);
                        acc[r][3] = fmaf(h, wa.w, acc[r][3]);
                        acc[r][4] = fmaf(h, wb.x, acc[r][4]);
                        acc[r][5] = fmaf(h, wb.y, acc[r][5]);
                        acc[r][6] = fmaf(h, wb.z, acc[r][6]);
                        acc[r][7] = fmaf(h, wb.w, acc[r][7]);
                    }
                }
            }
#pragma unroll
            for (int r = 0; r < 4; ++r) {
                *(float4*)&P_s[r][ks][p1c0] = make_float4(acc[r][0], acc[r][1], acc[r][2], acc[r][3]);
                *(float4*)&P_s[r][ks][p1c0 + 4] = make_float4(acc[r][4], acc[r][5], acc[r][6], acc[r][7]);
            }
        }
        __syncthreads();

        // ---- elementwise 1 (waves 0..3) ----
        if (wid < 4) {
            const float* uxr = UX + ((size_t)(b0 + row) * T_ + t) * IN_;
            float zr[4], rr[4], tmp[4];
#pragma unroll
            for (int q = 0; q < 4; ++q) {
                int j = lane + 64 * q;
                float sr = 0.f, sz = 0.f;
#pragma unroll
                for (int s = 0; s < 8; ++s) {
                    sr += P_s[row][s][j];
                    sz += P_s[row][s][256 + j];
                }
                rr[q] = sr; zr[q] = sz;
            }
            float hn = fmaxf(rnorm4(hreg), EPS_);
            // z gate
            mv_finish_reg(zr, hn);
#pragma unroll
            for (int q = 0; q < 4; ++q) tmp[q] = uxr[512 + lane + 64 * q];
            madd_reg(zr, tmp);
#pragma unroll
            for (int q = 0; q < 4; ++q) tmp[q] = bias_s[2][lane + 64 * q];
            madd_reg(zr, tmp);
            lsig_reg(zr);
#pragma unroll
            for (int q = 0; q < 4; ++q) zv[q] = zr[q];
            // r gate
            mv_finish_reg(rr, hn);
#pragma unroll
            for (int q = 0; q < 4; ++q) tmp[q] = uxr[lane + 64 * q];
            madd_reg(rr, tmp);
#pragma unroll
            for (int q = 0; q < 4; ++q) tmp[q] = bias_s[0][lane + 64 * q];
            madd_reg(rr, tmp);
            lsig_reg(rr);
            // rh
            float rh[4];
            pmul_reg(rr, hreg, rh, &rhn);
#pragma unroll
            for (int q = 0; q < 4; ++q) C32[row][lane + 64 * q] = rh[q];
        }
        __syncthreads();

        // ---- phase2: raw rh @ W_hhh^T ----
        {
            float acc2[4][4];
#pragma unroll
            for (int r = 0; r < 4; ++r)
#pragma unroll
                for (int c = 0; c < 4; ++c) acc2[r][c] = 0.f;
            for (int kk = 0; kk < 32; kk += 4) {
                int k = k20 + kk;
                float4 cv[4];
#pragma unroll
                for (int r = 0; r < 4; ++r) cv[r] = *(const float4*)&C32[r][k];
#pragma unroll
                for (int i = 0; i < 4; ++i) {
                    const float4 w = *(const float4*)&w2[(size_t)(k + i) * 768];
#pragma unroll
                    for (int r = 0; r < 4; ++r) {
                        const float c = ((const float*)&cv[r])[i];
                        acc2[r][0] = fmaf(c, w.x, acc2[r][0]);
                        acc2[r][1] = fmaf(c, w.y, acc2[r][1]);
                        acc2[r][2] = fmaf(c, w.z, acc2[r][2]);
                        acc2[r][3] = fmaf(c, w.w, acc2[r][3]);
                    }
                }
            }
#pragma unroll
            for (int r = 0; r < 4; ++r)
                *(float4*)&P_s[r][ks][p2c0] = make_float4(acc2[r][0], acc2[r][1], acc2[r][2], acc2[r][3]);
        }
        __syncthreads();

        // ---- elementwise 2 (waves 0..3): h update ----
        if (wid < 4) {
            const float* uxr = UX + ((size_t)(b0 + row) * T_ + t) * IN_;
            float ht[4], tmp[4];
#pragma unroll
            for (int q = 0; q < 4; ++q) {
                int j = lane + 64 * q;
                float sh = 0.f;
#pragma unroll
                for (int s = 0; s < 8; ++s) sh += P_s[row][s][j];
                ht[q] = sh;
            }
            mv_finish_reg(ht, rhn);
#pragma unroll
            for (int q = 0; q < 4; ++q) tmp[q] = uxr[256 + lane + 64 * q];
            madd_reg(ht, tmp);
#pragma unroll
            for (int q = 0; q < 4; ++q) tmp[q] = bias_s[1][lane + 64 * q];
            madd_reg(ht, tmp);                 // ht = h_tilde
            float dl[4];
#pragma unroll
            for (int q = 0; q < 4; ++q) dl[q] = -hreg[q];
            madd_reg(dl, ht);                  // delta = mobius_add(-h, h_tilde)
            float dv[4];
            pmul_reg(zv, dl, dv, nullptr);     // z (*) delta
            madd_reg(hreg, dv);                // h = mobius_add(h, ...)
            float* orow = Hfull + ((size_t)(b0 + row) * T_ + t) * H_;
#pragma unroll
            for (int q = 0; q < 4; ++q) {
                int j = lane + 64 * q;
                h32[row][j] = hreg[q];
                orow[j] = hreg[q];
            }
        }
        __syncthreads();
    }
}

// logmap0 in place over (rows, 256)
__global__ __launch_bounds__(256) void k_logmap(float* __restrict__ Y) {
    int wid = threadIdx.x >> 6, lane = threadIdx.x & 63;
    int row = blockIdx.x * 4 + wid;
    float* p = Y + (size_t)row * H_;
    float v0 = p[lane], v1 = p[lane + 64], v2 = p[lane + 128], v3 = p[lane + 192];
    float ss = wred(v0 * v0 + v1 * v1 + v2 * v2 + v3 * v3);
    float n = fmaxf(sqrtf(fmaxf(ss, 1e-15f)), EPS_);
    float s = artanh_(n) / n;
    p[lane] = v0 * s; p[lane + 64] = v1 * s; p[lane + 128] = v2 * s; p[lane + 192] = v3 * s;
}

// score[b,t] = v . tanh(S1 + b1 + q[b]) + bv, masked
__global__ __launch_bounds__(256) void k_score(
    const float* __restrict__ S1, const float* __restrict__ q,
    const float* __restrict__ b1, const float* __restrict__ av,
    const float* __restrict__ abv, const int* __restrict__ len,
    float* __restrict__ sc)
{
    int wid = threadIdx.x >> 6, lane = threadIdx.x & 63;
    int row = blockIdx.x * 4 + wid;
    int b = row / T_, t = row - b * T_;
    const float* s1 = S1 + (size_t)row * H_;
    const float* qp = q + (size_t)b * H_;
    float part = 0.f;
#pragma unroll
    for (int qq = 0; qq < 4; ++qq) {
        int j = lane + 64 * qq;
        float u = tanhf(s1[j] + b1[j] + qp[j]);
        part = fmaf(u, av[j], part);
    }
    part = wred(part) + abv[0];
    if (t >= len[b]) part = -1e9f;
    if (lane == 0) sc[row] = part;
}

// per-b: softmax over T, ctx = sum w*full, span logits + softmax -> d_out
__global__ __launch_bounds__(256) void k_ctx(
    const float* __restrict__ sc, const float* __restrict__ full,
    const float* __restrict__ spw, const float* __restrict__ spb,
    float* __restrict__ ctx, float* __restrict__ outsp)
{
    int b = blockIdx.x, tid = threadIdx.x;
    __shared__ float w_s[T_];
    __shared__ float cs[H_];
    __shared__ float red[NSPAN];
    if (tid < T_) w_s[tid] = sc[b * T_ + tid];
    __syncthreads();
    if (tid == 0) {
        float mx = -1e30f;
        for (int t = 0; t < T_; ++t) mx = fmaxf(mx, w_s[t]);
        float sum = 0.f;
        for (int t = 0; t < T_; ++t) { float e = expf(w_s[t] - mx); w_s[t] = e; sum += e; }
        float inv = 1.f / sum;
        for (int t = 0; t < T_; ++t) w_s[t] *= inv;
    }
    __syncthreads();
    float c = 0.f;
    for (int t = 0; t < T_; ++t) c = fmaf(w_s[t], full[((size_t)b * T_ + t) * H_ + tid], c);
    ctx[(size_t)b * H_ + tid] = c;
    cs[tid] = c;
    __syncthreads();
    if (tid < NSPAN) {
        float lg = spb[tid];
        for (int j = 0; j < H_; ++j) lg = fmaf(spw[tid * H_ + j], cs[j], lg);
        red[tid] = lg;
    }
    __syncthreads();
    if (tid == 0) {
        float mx = red[0];
        for (int k2 = 1; k2 < NSPAN; ++k2) mx = fmaxf(mx, red[k2]);
        float sum = 0.f;
        for (int k2 = 0; k2 < NSPAN; ++k2) sum += expf(red[k2] - mx);
        float inv = 1.f / sum;
        for (int k2 = 0; k2 < NSPAN; ++k2) outsp[(size_t)b * NSPAN + k2] = expf(red[k2] - mx) * inv;
    }
}

// Euclidean GRU cell + fc_out softmax
__global__ __launch_bounds__(256) void k_dec_cell(
    const float* __restrict__ gi, const float* __restrict__ gh,
    float* __restrict__ h, const float* __restrict__ fow,
    const float* __restrict__ fob, float* __restrict__ outp, int t)
{
    int b = blockIdx.x, j = threadIdx.x;
    __shared__ float hs[H_];
    __shared__ float red[2];
    size_t gb = (size_t)b * 768;
    float r = sigm_(gi[gb + j] + gh[gb + j]);
    float z = sigm_(gi[gb + 256 + j] + gh[gb + 256 + j]);
    float n = tanhf(fmaf(r, gh[gb + 512 + j], gi[gb + 512 + j]));
    float hv = h[(size_t)b * H_ + j];
    float hnew = (1.f - z) * n + z * hv;
    h[(size_t)b * H_ + j] = hnew;
    hs[j] = hnew;
    __syncthreads();
    int wid = j >> 6, lane = j & 63;
    if (wid < 2) {
        float p = 0.f;
#pragma unroll
        for (int q = 0; q < 4; ++q) { int c = lane + 64 * q; p = fmaf(fow[wid * H_ + c], hs[c], p); }
        p = wred(p);
        if (lane == 0) red[wid] = p + fob[wid];
    }
    __syncthreads();
    if (j == 0) {
        float l0 = red[0], l1 = red[1];
        float mx = fmaxf(l0, l1);
        float e0 = expf(l0 - mx), e1 = expf(l1 - mx);
        float inv = 1.f / (e0 + e1);
        outp[(size_t)b * (NDAYS * OUTD) + t * OUTD + 0] = e0 * inv;
        outp[(size_t)b * (NDAYS * OUTD) + t * OUTD + 1] = e1 * inv;
    }
}

extern "C" void kernel_launch(void* const* d_in, const int* in_sizes, int n_in,
                              void* d_out, int out_size, void* d_ws, size_t ws_size,
                              hipStream_t stream)
{
    (void)in_sizes; (void)n_in; (void)out_size; (void)ws_size;
    const float* x        = (const float*)d_in[0];
    const int*   len      = (const int*)  d_in[1];
    const float* enc_w_ih = (const float*)d_in[2];
    const float* enc_w_hh = (const float*)d_in[3];
    const float* enc_bias = (const float*)d_in[4];
    const float* dec_w_ih = (const float*)d_in[5];
    const float* dec_w_hh = (const float*)d_in[6];
    const float* dec_b_ih = (const float*)d_in[7];
    const float* dec_b_hh = (const float*)d_in[8];
    const float* attn_w1  = (const float*)d_in[9];
    const float* attn_b1  = (const float*)d_in[10];
    const float* attn_w2  = (const float*)d_in[11];
    const float* attn_b2  = (const float*)d_in[12];
    const float* attn_v   = (const float*)d_in[13];
    const float* attn_bv  = (const float*)d_in[14];
    const float* fc_in_w  = (const float*)d_in[15];
    const float* fc_in_b  = (const float*)d_in[16];
    const float* fc_out_w = (const float*)d_in[17];
    const float* fc_out_b = (const float*)d_in[18];
    const float* span_w   = (const float*)d_in[19];
    const float* span_b   = (const float*)d_in[20];
    float* out = (float*)d_out;
    float* wsf = (float*)d_ws;

    const size_t ROWS = (size_t)B_ * T_;            // 38400
    float* UX    = wsf;                             // 38400*768
    float* Hfull = UX + ROWS * IN_;                 // 38400*256
    float* xs    = Hfull + ROWS * H_;               // 38400
    float* xnb   = xs + ROWS;                       // 38400
    float* WT    = xnb + ROWS;                      // 256*768
    float* bvv   = WT + 256 * 768;                  // 768
    float* qbuf  = bvv + 768;                       // 512*256
    float* scb   = qbuf + (size_t)B_ * H_;          // 38400
    float* ctx   = scb + ROWS;                      // 512*256 (doubles as decoder h)
    // UX region reused after encoder/attention consume it:
    float* S1  = UX;
    float* gi  = UX;
    float* gh  = UX + (size_t)B_ * 768;
    float* inp = UX + 2 * (size_t)B_ * 768;

    k_bias<<<1, 256, 0, stream>>>(enc_bias, bvv);
    k_transpose<<<256, 256, 0, stream>>>(enc_w_hh, WT);
    k_row_scale<<<(unsigned)(ROWS / 4), 256, 0, stream>>>(x, xs, xnb);
    k_gemm_bt<<<dim3(IN_ / BN, (unsigned)(ROWS / BM)), 256, 0, stream>>>(x, IN_, enc_w_ih, nullptr, UX, IN_, IN_, 0);
    k_ux_scale<<<(unsigned)(ROWS * 3 / 4), 256, 0, stream>>>(UX, xs, xnb);
    k_encoder<<<B_ / 4, 512, 0, stream>>>(UX, WT, bvv, Hfull);
    k_logmap<<<(unsigned)(ROWS / 4), 256, 0, stream>>>(Hfull);
    // q = hx @ w2^T + b2   (hx rows are the t=T-1 rows of logmapped Hfull, stride T*H)
    k_gemm_bt64<<<dim3(H_ / 64, B_ / 64), 256, 0, stream>>>(Hfull + (T_ - 1) * H_, T_ * H_, attn_w2, attn_b2, qbuf, H_, H_, 0);
    k_gemm_bt<<<dim3(H_ / BN, (unsigned)(ROWS / BM)), 256, 0, stream>>>(Hfull, H_, attn_w1, nullptr, S1, H_, H_, 0);
    k_score<<<(unsigned)(ROWS / 4), 256, 0, stream>>>(S1, qbuf, attn_b1, attn_v, attn_bv, len, scb);
    k_ctx<<<B_, 256, 0, stream>>>(scb, Hfull, span_w, span_b, ctx, out);
    hipMemsetAsync(inp, 0, (size_t)B_ * 768 * sizeof(float), stream);
    for (int t = 0; t < NDAYS; ++t) {
        k_gemm_bt64<<<dim3(768 / 64, B_ / 64), 256, 0, stream>>>(inp, 768, dec_w_ih, dec_b_ih, gi, 768, 768, 0);
        k_gemm_bt64<<<dim3(768 / 64, B_ / 64), 256, 0, stream>>>(ctx, H_, dec_w_hh, dec_b_hh, gh, 768, H_, 0);
        k_dec_cell<<<B_, 256, 0, stream>>>(gi, gh, ctx, fc_out_w, fc_out_b, out + B_ * NSPAN, t);
        if (t + 1 < NDAYS)
            k_gemm_bt64<<<dim3(768 / 64, B_ / 64), 256, 0, stream>>>(ctx, H_, fc_in_w, fc_in_b, inp, 768, H_, 1);
    }
}

// Round 3
// 2514.541 us; speedup vs baseline: 2.0739x; 2.0294x over previous
//
#include <hip/hip_runtime.h>
#include <math.h>

#define B_    512
#define T_    75
#define IN_   768
#define H_    256
#define NSPAN 8
#define OUTD  2
#define NDAYS 10
#define EPS_  1e-5f
#define MAXN_ 0.999f
#define CLIP_ (1.0f - 1e-7f)

// ---------------- wave helpers (wave = 64 lanes) ----------------
__device__ __forceinline__ float wred(float v) {
#pragma unroll
    for (int o = 32; o > 0; o >>= 1) v += __shfl_xor(v, o, 64);
    return v;
}
__device__ __forceinline__ float artanh_(float x) {
    x = fminf(x, CLIP_);
    return 0.5f * logf((1.f + x) / (1.f - x));
}
__device__ __forceinline__ float sigm_(float x) { return 1.f / (1.f + expf(-x)); }

// -------- register-array mobius primitives (one wave owns a 256-vector, 4/lane) --------
__device__ __forceinline__ float rnorm4(const float* v) {
    float ss = 0.f;
#pragma unroll
    for (int q = 0; q < 4; ++q) ss = fmaf(v[q], v[q], ss);
    ss = wred(ss);
    return sqrtf(fmaxf(ss, 1e-15f));
}
__device__ __forceinline__ void mv_finish_reg(float* v, float xn) {
    float n = fmaxf(rnorm4(v), EPS_);
    float tt = tanhf(n / xn * artanh_(xn));
    float sc = tt / n;
    if (tt > MAXN_) sc = MAXN_ / n;
#pragma unroll
    for (int q = 0; q < 4; ++q) v[q] *= sc;
}
__device__ __forceinline__ void madd_reg(float* x, const float* y) {
    float x2 = 0.f, y2 = 0.f, xy = 0.f;
#pragma unroll
    for (int q = 0; q < 4; ++q) {
        x2 = fmaf(x[q], x[q], x2);
        y2 = fmaf(y[q], y[q], y2);
        xy = fmaf(x[q], y[q], xy);
    }
    x2 = wred(x2); y2 = wred(y2); xy = wred(xy);
    float den = fmaxf(1.f + 2.f * xy + x2 * y2, EPS_);
    float cx = 1.f + 2.f * xy + y2, cy = 1.f - x2;
    float nn = 0.f;
#pragma unroll
    for (int q = 0; q < 4; ++q) {
        float nv = cx * x[q] + cy * y[q];
        x[q] = nv;
        nn = fmaf(nv, nv, nn);
    }
    nn = wred(nn);
    float pn = sqrtf(fmaxf(nn, 1e-15f)) / den;
    float s = 1.f / den;
    if (pn > MAXN_) s *= MAXN_ / pn;
#pragma unroll
    for (int q = 0; q < 4; ++q) x[q] *= s;
}
__device__ __forceinline__ void lsig_reg(float* v) {
    float n = fmaxf(rnorm4(v), EPS_);
    float s = artanh_(n) / n;
#pragma unroll
    for (int q = 0; q < 4; ++q) v[q] = 1.f / (1.f + expf(-v[q] * s));
}
__device__ __forceinline__ void pmul_reg(const float* w, const float* x, float* o, float* onorm) {
    float xn = fmaxf(rnorm4(x), EPS_);
#pragma unroll
    for (int q = 0; q < 4; ++q) o[q] = w[q] * x[q];
    float wxn = fmaxf(rnorm4(o), EPS_);
    float tt = tanhf(wxn / xn * artanh_(xn));
    float sc = tt / wxn;
    float nrm = tt;
    if (tt > MAXN_) { sc = MAXN_ / wxn; nrm = MAXN_; }
#pragma unroll
    for (int q = 0; q < 4; ++q) o[q] *= sc;
    if (onorm) *onorm = fmaxf(nrm, EPS_);
}

// ---------------- prep kernels ----------------
__global__ __launch_bounds__(256) void k_bias(const float* __restrict__ eb, float* __restrict__ bv) {
    int wid = threadIdx.x >> 6, lane = threadIdx.x & 63;
    if (wid >= 3) return;
    const float* p = eb + wid * H_;
    float v0 = p[lane], v1 = p[lane + 64], v2 = p[lane + 128], v3 = p[lane + 192];
    float ss = wred(v0 * v0 + v1 * v1 + v2 * v2 + v3 * v3);
    float n = sqrtf(fmaxf(ss, 1e-15f));
    float nc = fmaxf(n, EPS_);
    float s = tanhf(nc) / nc;
    float nv = n * s;
    if (nv > MAXN_) s *= MAXN_ / nv;
    bv[wid * H_ + lane] = v0 * s;
    bv[wid * H_ + lane + 64] = v1 * s;
    bv[wid * H_ + lane + 128] = v2 * s;
    bv[wid * H_ + lane + 192] = v3 * s;
}

__global__ __launch_bounds__(256) void k_transpose(const float* __restrict__ W, float* __restrict__ WT) {
    int k = blockIdx.x; // 0..255
    for (int j = threadIdx.x; j < 768; j += 256)
        WT[(size_t)k * 768 + j] = W[(size_t)j * 256 + k];
}

__global__ __launch_bounds__(256) void k_row_scale(const float* __restrict__ x, float* __restrict__ xs, float* __restrict__ xn) {
    int wid = threadIdx.x >> 6, lane = threadIdx.x & 63;
    int row = blockIdx.x * 4 + wid;
    const float* p = x + (size_t)row * IN_;
    float ss = 0.f;
#pragma unroll
    for (int q = 0; q < 12; ++q) { float v = p[lane + 64 * q]; ss = fmaf(v, v, ss); }
    ss = wred(ss);
    float n = sqrtf(fmaxf(ss, 1e-15f));
    float nc = fmaxf(n, EPS_);
    float s = tanhf(nc) / nc;
    float nv = n * s;
    if (nv > MAXN_) s *= MAXN_ / nv;
    if (lane == 0) { xs[row] = s; xn[row] = fmaxf(n * s, EPS_); }
}

__global__ __launch_bounds__(256) void k_ux_scale(float* __restrict__ MX, const float* __restrict__ xs, const float* __restrict__ xnb) {
    int wid = threadIdx.x >> 6, lane = threadIdx.x & 63;
    int rg = blockIdx.x * 4 + wid;
    int row = rg / 3, g = rg - row * 3;
    float s = xs[row], xv = xnb[row];
    float* p = MX + (size_t)row * IN_ + g * H_;
    float v0 = p[lane] * s, v1 = p[lane + 64] * s, v2 = p[lane + 128] * s, v3 = p[lane + 192] * s;
    float ss = wred(v0 * v0 + v1 * v1 + v2 * v2 + v3 * v3);
    float mxn = fmaxf(sqrtf(fmaxf(ss, 1e-15f)), EPS_);
    float tt = tanhf(mxn / xv * artanh_(xv));
    float sc = tt / mxn;
    if (tt > MAXN_) sc = MAXN_ / mxn;
    p[lane] = v0 * sc; p[lane + 64] = v1 * sc; p[lane + 128] = v2 * sc; p[lane + 192] = v3 * sc;
}

// ---------------- generic f32 GEMM (128x128 tile): C = A @ B^T (+bias)(+relu) ----------------
#define BM 128
#define BN 128
#define BKK 16
__global__ __launch_bounds__(256) void k_gemm_bt(
    const float* __restrict__ A, int lda,
    const float* __restrict__ Bm,
    const float* __restrict__ bias,
    float* __restrict__ C,
    int N, int K, int act)
{
    __shared__ float As[BKK][BM + 4];
    __shared__ float Bs[BKK][BN + 4];
    int tid = threadIdx.x;
    int m0 = blockIdx.y * BM, n0 = blockIdx.x * BN;
    int lr = tid >> 2;
    int lc = (tid & 3) << 2;
    int row0 = (tid >> 4) << 3;
    int col0 = (tid & 15) << 3;
    float acc[8][8];
#pragma unroll
    for (int i = 0; i < 8; ++i)
#pragma unroll
        for (int j = 0; j < 8; ++j) acc[i][j] = 0.f;

    for (int k0 = 0; k0 < K; k0 += BKK) {
        float4 a0 = *(const float4*)&A[(size_t)(m0 + lr) * lda + k0 + lc];
        float4 a1 = *(const float4*)&A[(size_t)(m0 + lr + 64) * lda + k0 + lc];
        float4 b0 = *(const float4*)&Bm[(size_t)(n0 + lr) * K + k0 + lc];
        float4 b1 = *(const float4*)&Bm[(size_t)(n0 + lr + 64) * K + k0 + lc];
        __syncthreads();
        As[lc + 0][lr] = a0.x; As[lc + 1][lr] = a0.y; As[lc + 2][lr] = a0.z; As[lc + 3][lr] = a0.w;
        As[lc + 0][lr + 64] = a1.x; As[lc + 1][lr + 64] = a1.y; As[lc + 2][lr + 64] = a1.z; As[lc + 3][lr + 64] = a1.w;
        Bs[lc + 0][lr] = b0.x; Bs[lc + 1][lr] = b0.y; Bs[lc + 2][lr] = b0.z; Bs[lc + 3][lr] = b0.w;
        Bs[lc + 0][lr + 64] = b1.x; Bs[lc + 1][lr + 64] = b1.y; Bs[lc + 2][lr + 64] = b1.z; Bs[lc + 3][lr + 64] = b1.w;
        __syncthreads();
#pragma unroll
        for (int k = 0; k < BKK; ++k) {
            float4 x0 = *(const float4*)&As[k][row0];
            float4 x1 = *(const float4*)&As[k][row0 + 4];
            float4 y0 = *(const float4*)&Bs[k][col0];
            float4 y1 = *(const float4*)&Bs[k][col0 + 4];
            float xa[8] = {x0.x, x0.y, x0.z, x0.w, x1.x, x1.y, x1.z, x1.w};
            float yb[8] = {y0.x, y0.y, y0.z, y0.w, y1.x, y1.y, y1.z, y1.w};
#pragma unroll
            for (int i = 0; i < 8; ++i)
#pragma unroll
                for (int j = 0; j < 8; ++j) acc[i][j] = fmaf(xa[i], yb[j], acc[i][j]);
        }
    }
    float bvv[8];
#pragma unroll
    for (int j = 0; j < 8; ++j) bvv[j] = bias ? bias[n0 + col0 + j] : 0.f;
#pragma unroll
    for (int i = 0; i < 8; ++i) {
        float vv[8];
#pragma unroll
        for (int j = 0; j < 8; ++j) {
            float v = acc[i][j] + bvv[j];
            vv[j] = act ? fmaxf(v, 0.f) : v;
        }
        size_t base = (size_t)(m0 + row0 + i) * N + n0 + col0;
        *(float4*)&C[base] = make_float4(vv[0], vv[1], vv[2], vv[3]);
        *(float4*)&C[base + 4] = make_float4(vv[4], vv[5], vv[6], vv[7]);
    }
}

// ---------------- small-tile f32 GEMM (64x64, BK=32, 256 thr) for M=512 layers ----------------
__global__ __launch_bounds__(256) void k_gemm_bt64(
    const float* __restrict__ A, int lda,
    const float* __restrict__ Bm,
    const float* __restrict__ bias,
    float* __restrict__ C,
    int N, int K, int act)
{
    __shared__ float As[32][64 + 4];
    __shared__ float Bs[32][64 + 4];
    int tid = threadIdx.x;
    int m0 = blockIdx.y * 64, n0 = blockIdx.x * 64;
    int lr = tid >> 2;            // 0..63
    int lc = (tid & 3) << 3;      // 0,8,16,24
    int row0 = (tid >> 4) << 2;   // 0..60
    int col0 = (tid & 15) << 2;   // 0..60
    float acc[4][4];
#pragma unroll
    for (int i = 0; i < 4; ++i)
#pragma unroll
        for (int j = 0; j < 4; ++j) acc[i][j] = 0.f;

    for (int k0 = 0; k0 < K; k0 += 32) {
        float4 a0 = *(const float4*)&A[(size_t)(m0 + lr) * lda + k0 + lc];
        float4 a1 = *(const float4*)&A[(size_t)(m0 + lr) * lda + k0 + lc + 4];
        float4 b0 = *(const float4*)&Bm[(size_t)(n0 + lr) * K + k0 + lc];
        float4 b1 = *(const float4*)&Bm[(size_t)(n0 + lr) * K + k0 + lc + 4];
        __syncthreads();
        As[lc + 0][lr] = a0.x; As[lc + 1][lr] = a0.y; As[lc + 2][lr] = a0.z; As[lc + 3][lr] = a0.w;
        As[lc + 4][lr] = a1.x; As[lc + 5][lr] = a1.y; As[lc + 6][lr] = a1.z; As[lc + 7][lr] = a1.w;
        Bs[lc + 0][lr] = b0.x; Bs[lc + 1][lr] = b0.y; Bs[lc + 2][lr] = b0.z; Bs[lc + 3][lr] = b0.w;
        Bs[lc + 4][lr] = b1.x; Bs[lc + 5][lr] = b1.y; Bs[lc + 6][lr] = b1.z; Bs[lc + 7][lr] = b1.w;
        __syncthreads();
#pragma unroll
        for (int k = 0; k < 32; ++k) {
            float4 xa = *(const float4*)&As[k][row0];
            float4 yb = *(const float4*)&Bs[k][col0];
            float xv[4] = {xa.x, xa.y, xa.z, xa.w};
            float yv[4] = {yb.x, yb.y, yb.z, yb.w};
#pragma unroll
            for (int i = 0; i < 4; ++i)
#pragma unroll
                for (int j = 0; j < 4; ++j) acc[i][j] = fmaf(xv[i], yv[j], acc[i][j]);
        }
    }
    float bvv[4];
#pragma unroll
    for (int j = 0; j < 4; ++j) bvv[j] = bias ? bias[n0 + col0 + j] : 0.f;
#pragma unroll
    for (int i = 0; i < 4; ++i) {
        float vv[4];
#pragma unroll
        for (int j = 0; j < 4; ++j) {
            float v = acc[i][j] + bvv[j];
            vv[j] = act ? fmaxf(v, 0.f) : v;
        }
        *(float4*)&C[(size_t)(m0 + row0 + i) * N + n0 + col0] = make_float4(vv[0], vv[1], vv[2], vv[3]);
    }
}

// ---------------- mobius GRU encoder v3: 4 rows/block, 128 blocks ----------------
// Low-register tiling: phase1 = 4 cols x 64-k slice per thread (acc[4][4]);
// phase2 = 2 cols x 64-k slice per thread (acc[4][2]). Weight loads are lane-contiguous
// float4/float2 (fully coalesced). Partials P[4 rows][4 slices][512 cols] in LDS.
__global__ __launch_bounds__(512) void k_encoder(
    const float* __restrict__ UX, const float* __restrict__ WT,
    const float* __restrict__ bv, float* __restrict__ Hfull)
{
    __shared__ float h32[4][256];
    __shared__ float C32[4][256];
    __shared__ float P_s[4][4][512];    // 32KB partials (phase1 cols<512, phase2 cols<256)
    __shared__ float bias_s[3][256];

    int tid = threadIdx.x;
    int wid = tid >> 6, lane = tid & 63;
    int b0 = blockIdx.x * 4;

    for (int i = tid; i < 768; i += 512) bias_s[i >> 8][i & 255] = bv[i];
    for (int i = tid; i < 1024; i += 512) ((float*)h32)[i] = 0.f;
    __syncthreads();

    // phase1 mapping: cg = tid&127 (4 cols each), ks = tid>>7 (64-k slice)
    int cg = tid & 127, ks = tid >> 7;
    int p1c0 = cg * 4;                             // 0..508 in P-col space
    int wcol1 = (p1c0 < 256) ? p1c0 : p1c0 + 256;  // r cols 0..255 / z cols 512..767
    const float* w1 = WT + wcol1;
    // phase2 mapping: 2 cols each
    int p2c0 = cg * 2;                             // 0..254
    const float* w2 = WT + 256 + p2c0;             // h cols 256..511
    int kbase = ks * 64;

    int row = wid;  // elementwise row (valid when wid<4)
    float hreg[4] = {0.f, 0.f, 0.f, 0.f};
    float zv[4];
    float rhn = EPS_;

    for (int t = 0; t < T_; ++t) {
        // ---- phase1: raw h @ {W_hr, W_hz}^T ----
        {
            float a0[4] = {0,0,0,0}, a1[4] = {0,0,0,0}, a2[4] = {0,0,0,0}, a3[4] = {0,0,0,0};
            for (int kk = 0; kk < 64; kk += 4) {
                int k = kbase + kk;
                float4 hv0 = *(const float4*)&h32[0][k];
                float4 hv1 = *(const float4*)&h32[1][k];
                float4 hv2 = *(const float4*)&h32[2][k];
                float4 hv3 = *(const float4*)&h32[3][k];
#pragma unroll
                for (int i = 0; i < 4; ++i) {
                    const float4 w = *(const float4*)&w1[(size_t)(k + i) * 768];
                    float e0 = ((const float*)&hv0)[i];
                    float e1 = ((const float*)&hv1)[i];
                    float e2 = ((const float*)&hv2)[i];
                    float e3 = ((const float*)&hv3)[i];
                    a0[0] = fmaf(e0, w.x, a0[0]); a0[1] = fmaf(e0, w.y, a0[1]);
                    a0[2] = fmaf(e0, w.z, a0[2]); a0[3] = fmaf(e0, w.w, a0[3]);
                    a1[0] = fmaf(e1, w.x, a1[0]); a1[1] = fmaf(e1, w.y, a1[1]);
                    a1[2] = fmaf(e1, w.z, a1[2]); a1[3] = fmaf(e1, w.w, a1[3]);
                    a2[0] = fmaf(e2, w.x, a2[0]); a2[1] = fmaf(e2, w.y, a2[1]);
                    a2[2] = fmaf(e2, w.z, a2[2]); a2[3] = fmaf(e2, w.w, a2[3]);
                    a3[0] = fmaf(e3, w.x, a3[0]); a3[1] = fmaf(e3, w.y, a3[1]);
                    a3[2] = fmaf(e3, w.z, a3[2]); a3[3] = fmaf(e3, w.w, a3[3]);
                }
            }
            *(float4*)&P_s[0][ks][p1c0] = make_float4(a0[0], a0[1], a0[2], a0[3]);
            *(float4*)&P_s[1][ks][p1c0] = make_float4(a1[0], a1[1], a1[2], a1[3]);
            *(float4*)&P_s[2][ks][p1c0] = make_float4(a2[0], a2[1], a2[2], a2[3]);
            *(float4*)&P_s[3][ks][p1c0] = make_float4(a3[0], a3[1], a3[2], a3[3]);
        }
        __syncthreads();

        // ---- elementwise 1 (waves 0..3) ----
        if (wid < 4) {
            const float* uxr = UX + ((size_t)(b0 + row) * T_ + t) * IN_;
            float zr[4], rr[4], tmp[4];
#pragma unroll
            for (int q = 0; q < 4; ++q) {
                int j = lane + 64 * q;
                float sr = 0.f, sz = 0.f;
#pragma unroll
                for (int s = 0; s < 4; ++s) {
                    sr += P_s[row][s][j];
                    sz += P_s[row][s][256 + j];
                }
                rr[q] = sr; zr[q] = sz;
            }
            float hn = fmaxf(rnorm4(hreg), EPS_);
            // z gate
            mv_finish_reg(zr, hn);
#pragma unroll
            for (int q = 0; q < 4; ++q) tmp[q] = uxr[512 + lane + 64 * q];
            madd_reg(zr, tmp);
#pragma unroll
            for (int q = 0; q < 4; ++q) tmp[q] = bias_s[2][lane + 64 * q];
            madd_reg(zr, tmp);
            lsig_reg(zr);
#pragma unroll
            for (int q = 0; q < 4; ++q) zv[q] = zr[q];
            // r gate
            mv_finish_reg(rr, hn);
#pragma unroll
            for (int q = 0; q < 4; ++q) tmp[q] = uxr[lane + 64 * q];
            madd_reg(rr, tmp);
#pragma unroll
            for (int q = 0; q < 4; ++q) tmp[q] = bias_s[0][lane + 64 * q];
            madd_reg(rr, tmp);
            lsig_reg(rr);
            // rh
            float rh[4];
            pmul_reg(rr, hreg, rh, &rhn);
#pragma unroll
            for (int q = 0; q < 4; ++q) C32[row][lane + 64 * q] = rh[q];
        }
        __syncthreads();

        // ---- phase2: raw rh @ W_hhh^T ----
        {
            float c0[2] = {0,0}, c1[2] = {0,0}, c2[2] = {0,0}, c3[2] = {0,0};
            for (int kk = 0; kk < 64; kk += 4) {
                int k = kbase + kk;
                float4 cv0 = *(const float4*)&C32[0][k];
                float4 cv1 = *(const float4*)&C32[1][k];
                float4 cv2 = *(const float4*)&C32[2][k];
                float4 cv3 = *(const float4*)&C32[3][k];
#pragma unroll
                for (int i = 0; i < 4; ++i) {
                    const float2 w = *(const float2*)&w2[(size_t)(k + i) * 768];
                    float e0 = ((const float*)&cv0)[i];
                    float e1 = ((const float*)&cv1)[i];
                    float e2 = ((const float*)&cv2)[i];
                    float e3 = ((const float*)&cv3)[i];
                    c0[0] = fmaf(e0, w.x, c0[0]); c0[1] = fmaf(e0, w.y, c0[1]);
                    c1[0] = fmaf(e1, w.x, c1[0]); c1[1] = fmaf(e1, w.y, c1[1]);
                    c2[0] = fmaf(e2, w.x, c2[0]); c2[1] = fmaf(e2, w.y, c2[1]);
                    c3[0] = fmaf(e3, w.x, c3[0]); c3[1] = fmaf(e3, w.y, c3[1]);
                }
            }
            *(float2*)&P_s[0][ks][p2c0] = make_float2(c0[0], c0[1]);
            *(float2*)&P_s[1][ks][p2c0] = make_float2(c1[0], c1[1]);
            *(float2*)&P_s[2][ks][p2c0] = make_float2(c2[0], c2[1]);
            *(float2*)&P_s[3][ks][p2c0] = make_float2(c3[0], c3[1]);
        }
        __syncthreads();

        // ---- elementwise 2 (waves 0..3): h update ----
        if (wid < 4) {
            const float* uxr = UX + ((size_t)(b0 + row) * T_ + t) * IN_;
            float ht[4], tmp[4];
#pragma unroll
            for (int q = 0; q < 4; ++q) {
                int j = lane + 64 * q;
                float sh = 0.f;
#pragma unroll
                for (int s = 0; s < 4; ++s) sh += P_s[row][s][j];
                ht[q] = sh;
            }
            mv_finish_reg(ht, rhn);
#pragma unroll
            for (int q = 0; q < 4; ++q) tmp[q] = uxr[256 + lane + 64 * q];
            madd_reg(ht, tmp);
#pragma unroll
            for (int q = 0; q < 4; ++q) tmp[q] = bias_s[1][lane + 64 * q];
            madd_reg(ht, tmp);                 // ht = h_tilde
            float dl[4];
#pragma unroll
            for (int q = 0; q < 4; ++q) dl[q] = -hreg[q];
            madd_reg(dl, ht);                  // delta = mobius_add(-h, h_tilde)
            float dv[4];
            pmul_reg(zv, dl, dv, nullptr);     // z (*) delta
            madd_reg(hreg, dv);                // h = mobius_add(h, ...)
            float* orow = Hfull + ((size_t)(b0 + row) * T_ + t) * H_;
#pragma unroll
            for (int q = 0; q < 4; ++q) {
                int j = lane + 64 * q;
                h32[row][j] = hreg[q];
                orow[j] = hreg[q];
            }
        }
        __syncthreads();
    }
}

// logmap0 in place over (rows, 256)
__global__ __launch_bounds__(256) void k_logmap(float* __restrict__ Y) {
    int wid = threadIdx.x >> 6, lane = threadIdx.x & 63;
    int row = blockIdx.x * 4 + wid;
    float* p = Y + (size_t)row * H_;
    float v0 = p[lane], v1 = p[lane + 64], v2 = p[lane + 128], v3 = p[lane + 192];
    float ss = wred(v0 * v0 + v1 * v1 + v2 * v2 + v3 * v3);
    float n = fmaxf(sqrtf(fmaxf(ss, 1e-15f)), EPS_);
    float s = artanh_(n) / n;
    p[lane] = v0 * s; p[lane + 64] = v1 * s; p[lane + 128] = v2 * s; p[lane + 192] = v3 * s;
}

// score[b,t] = v . tanh(S1 + b1 + q[b]) + bv, masked
__global__ __launch_bounds__(256) void k_score(
    const float* __restrict__ S1, const float* __restrict__ q,
    const float* __restrict__ b1, const float* __restrict__ av,
    const float* __restrict__ abv, const int* __restrict__ len,
    float* __restrict__ sc)
{
    int wid = threadIdx.x >> 6, lane = threadIdx.x & 63;
    int row = blockIdx.x * 4 + wid;
    int b = row / T_, t = row - b * T_;
    const float* s1 = S1 + (size_t)row * H_;
    const float* qp = q + (size_t)b * H_;
    float part = 0.f;
#pragma unroll
    for (int qq = 0; qq < 4; ++qq) {
        int j = lane + 64 * qq;
        float u = tanhf(s1[j] + b1[j] + qp[j]);
        part = fmaf(u, av[j], part);
    }
    part = wred(part) + abv[0];
    if (t >= len[b]) part = -1e9f;
    if (lane == 0) sc[row] = part;
}

// per-b: softmax over T, ctx = sum w*full, span logits + softmax -> d_out
__global__ __launch_bounds__(256) void k_ctx(
    const float* __restrict__ sc, const float* __restrict__ full,
    const float* __restrict__ spw, const float* __restrict__ spb,
    float* __restrict__ ctx, float* __restrict__ outsp)
{
    int b = blockIdx.x, tid = threadIdx.x;
    __shared__ float w_s[T_];
    __shared__ float cs[H_];
    __shared__ float red[NSPAN];
    if (tid < T_) w_s[tid] = sc[b * T_ + tid];
    __syncthreads();
    if (tid == 0) {
        float mx = -1e30f;
        for (int t = 0; t < T_; ++t) mx = fmaxf(mx, w_s[t]);
        float sum = 0.f;
        for (int t = 0; t < T_; ++t) { float e = expf(w_s[t] - mx); w_s[t] = e; sum += e; }
        float inv = 1.f / sum;
        for (int t = 0; t < T_; ++t) w_s[t] *= inv;
    }
    __syncthreads();
    float c = 0.f;
    for (int t = 0; t < T_; ++t) c = fmaf(w_s[t], full[((size_t)b * T_ + t) * H_ + tid], c);
    ctx[(size_t)b * H_ + tid] = c;
    cs[tid] = c;
    __syncthreads();
    if (tid < NSPAN) {
        float lg = spb[tid];
        for (int j = 0; j < H_; ++j) lg = fmaf(spw[tid * H_ + j], cs[j], lg);
        red[tid] = lg;
    }
    __syncthreads();
    if (tid == 0) {
        float mx = red[0];
        for (int k2 = 1; k2 < NSPAN; ++k2) mx = fmaxf(mx, red[k2]);
        float sum = 0.f;
        for (int k2 = 0; k2 < NSPAN; ++k2) sum += expf(red[k2] - mx);
        float inv = 1.f / sum;
        for (int k2 = 0; k2 < NSPAN; ++k2) outsp[(size_t)b * NSPAN + k2] = expf(red[k2] - mx) * inv;
    }
}

// Euclidean GRU cell + fc_out softmax
__global__ __launch_bounds__(256) void k_dec_cell(
    const float* __restrict__ gi, const float* __restrict__ gh,
    float* __restrict__ h, const float* __restrict__ fow,
    const float* __restrict__ fob, float* __restrict__ outp, int t)
{
    int b = blockIdx.x, j = threadIdx.x;
    __shared__ float hs[H_];
    __shared__ float red[2];
    size_t gb = (size_t)b * 768;
    float r = sigm_(gi[gb + j] + gh[gb + j]);
    float z = sigm_(gi[gb + 256 + j] + gh[gb + 256 + j]);
    float n = tanhf(fmaf(r, gh[gb + 512 + j], gi[gb + 512 + j]));
    float hv = h[(size_t)b * H_ + j];
    float hnew = (1.f - z) * n + z * hv;
    h[(size_t)b * H_ + j] = hnew;
    hs[j] = hnew;
    __syncthreads();
    int wid = j >> 6, lane = j & 63;
    if (wid < 2) {
        float p = 0.f;
#pragma unroll
        for (int q = 0; q < 4; ++q) { int c = lane + 64 * q; p = fmaf(fow[wid * H_ + c], hs[c], p); }
        p = wred(p);
        if (lane == 0) red[wid] = p + fob[wid];
    }
    __syncthreads();
    if (j == 0) {
        float l0 = red[0], l1 = red[1];
        float mx = fmaxf(l0, l1);
        float e0 = expf(l0 - mx), e1 = expf(l1 - mx);
        float inv = 1.f / (e0 + e1);
        outp[(size_t)b * (NDAYS * OUTD) + t * OUTD + 0] = e0 * inv;
        outp[(size_t)b * (NDAYS * OUTD) + t * OUTD + 1] = e1 * inv;
    }
}

extern "C" void kernel_launch(void* const* d_in, const int* in_sizes, int n_in,
                              void* d_out, int out_size, void* d_ws, size_t ws_size,
                              hipStream_t stream)
{
    (void)in_sizes; (void)n_in; (void)out_size; (void)ws_size;
    const float* x        = (const float*)d_in[0];
    const int*   len      = (const int*)  d_in[1];
    const float* enc_w_ih = (const float*)d_in[2];
    const float* enc_w_hh = (const float*)d_in[3];
    const float* enc_bias = (const float*)d_in[4];
    const float* dec_w_ih = (const float*)d_in[5];
    const float* dec_w_hh = (const float*)d_in[6];
    const float* dec_b_ih = (const float*)d_in[7];
    const float* dec_b_hh = (const float*)d_in[8];
    const float* attn_w1  = (const float*)d_in[9];
    const float* attn_b1  = (const float*)d_in[10];
    const float* attn_w2  = (const float*)d_in[11];
    const float* attn_b2  = (const float*)d_in[12];
    const float* attn_v   = (const float*)d_in[13];
    const float* attn_bv  = (const float*)d_in[14];
    const float* fc_in_w  = (const float*)d_in[15];
    const float* fc_in_b  = (const float*)d_in[16];
    const float* fc_out_w = (const float*)d_in[17];
    const float* fc_out_b = (const float*)d_in[18];
    const float* span_w   = (const float*)d_in[19];
    const float* span_b   = (const float*)d_in[20];
    float* out = (float*)d_out;
    float* wsf = (float*)d_ws;

    const size_t ROWS = (size_t)B_ * T_;            // 38400
    float* UX    = wsf;                             // 38400*768
    float* Hfull = UX + ROWS * IN_;                 // 38400*256
    float* xs    = Hfull + ROWS * H_;               // 38400
    float* xnb   = xs + ROWS;                       // 38400
    float* WT    = xnb + ROWS;                      // 256*768
    float* bvv   = WT + 256 * 768;                  // 768
    float* qbuf  = bvv + 768;                       // 512*256
    float* scb   = qbuf + (size_t)B_ * H_;          // 38400
    float* ctx   = scb + ROWS;                      // 512*256 (doubles as decoder h)
    // UX region reused after encoder/attention consume it:
    float* S1  = UX;
    float* gi  = UX;
    float* gh  = UX + (size_t)B_ * 768;
    float* inp = UX + 2 * (size_t)B_ * 768;

    k_bias<<<1, 256, 0, stream>>>(enc_bias, bvv);
    k_transpose<<<256, 256, 0, stream>>>(enc_w_hh, WT);
    k_row_scale<<<(unsigned)(ROWS / 4), 256, 0, stream>>>(x, xs, xnb);
    k_gemm_bt<<<dim3(IN_ / BN, (unsigned)(ROWS / BM)), 256, 0, stream>>>(x, IN_, enc_w_ih, nullptr, UX, IN_, IN_, 0);
    k_ux_scale<<<(unsigned)(ROWS * 3 / 4), 256, 0, stream>>>(UX, xs, xnb);
    k_encoder<<<B_ / 4, 512, 0, stream>>>(UX, WT, bvv, Hfull);
    k_logmap<<<(unsigned)(ROWS / 4), 256, 0, stream>>>(Hfull);
    // q = hx @ w2^T + b2   (hx rows are the t=T-1 rows of logmapped Hfull, stride T*H)
    k_gemm_bt64<<<dim3(H_ / 64, B_ / 64), 256, 0, stream>>>(Hfull + (T_ - 1) * H_, T_ * H_, attn_w2, attn_b2, qbuf, H_, H_, 0);
    k_gemm_bt<<<dim3(H_ / BN, (unsigned)(ROWS / BM)), 256, 0, stream>>>(Hfull, H_, attn_w1, nullptr, S1, H_, H_, 0);
    k_score<<<(unsigned)(ROWS / 4), 256, 0, stream>>>(S1, qbuf, attn_b1, attn_v, attn_bv, len, scb);
    k_ctx<<<B_, 256, 0, stream>>>(scb, Hfull, span_w, span_b, ctx, out);
    hipMemsetAsync(inp, 0, (size_t)B_ * 768 * sizeof(float), stream);
    for (int t = 0; t < NDAYS; ++t) {
        k_gemm_bt64<<<dim3(768 / 64, B_ / 64), 256, 0, stream>>>(inp, 768, dec_w_ih, dec_b_ih, gi, 768, 768, 0);
        k_gemm_bt64<<<dim3(768 / 64, B_ / 64), 256, 0, stream>>>(ctx, H_, dec_w_hh, dec_b_hh, gh, 768, H_, 0);
        k_dec_cell<<<B_, 256, 0, stream>>>(gi, gh, ctx, fc_out_w, fc_out_b, out + B_ * NSPAN, t);
        if (t + 1 < NDAYS)
            k_gemm_bt64<<<dim3(768 / 64, B_ / 64), 256, 0, stream>>>(ctx, H_, fc_in_w, fc_in_b, inp, 768, H_, 1);
    }
}